// Round 16
// baseline (793.255 us; speedup 1.0000x reference)
//
#include <hip/hip_runtime.h>
#include <hip/hip_bf16.h>

// LinearFLH: out[m,n] = sx[m]*sw[n]*(x[m,:].w[n,:]) + bias[n]
// M=8192, N=11008, K=4096. All harness buffers FLOAT32 (fp16 ref -> "else
// float" rule). Pipeline: (1) f32->bf16 convert of X,W into d_ws, (2) 256x256
// BK=64 bf16 MFMA GEMM, 8 waves, R14-champion schedule (4-phase counted-vmcnt,
// 1 barrier/phase, K-synchronized 2D cluster map), but with
// *** v_mfma_f32_32x32x16_bf16 *** instead of 16x16x32:
//   - measured ceiling 2382 vs 2075 TF (m06/m119) -> floor 2484->~2160 cy/tile
//   - 32 vs 64 MFMA insts/wave/tile -> half the issue slots, more co-issue room
// Same LDS layout/swizzle/stages/waits as R14 (699us champion).
// R15 lesson: 2-barrier m201 bracket regressed (726us); 1-barrier phases win here.

#define M_DIM 8192
#define N_DIM 11008
#define K_DIM 4096
#define BM 256
#define BN 256
#define BK 64
#define NT (K_DIM / BK)                       // 64 K-tiles
#define NWG ((M_DIM / BM) * (N_DIM / BN))     // 32*43 = 1376

#define X_ELEMS (M_DIM * K_DIM)
#define W_ELEMS (N_DIM * K_DIM)
#define WS_NEEDED ((size_t)(X_ELEMS + W_ELEMS) * 2)

typedef __bf16 bf16x8 __attribute__((ext_vector_type(8)));
typedef float f32x4 __attribute__((ext_vector_type(4)));
typedef float f32x16 __attribute__((ext_vector_type(16)));
typedef unsigned short u16x4 __attribute__((ext_vector_type(4)));
typedef unsigned short u16x8 __attribute__((ext_vector_type(8)));

typedef __attribute__((address_space(3))) void lds_void;
typedef const __attribute__((address_space(1))) void gmem_void;

// f32 -> bf16 bits, round-to-nearest-even (inputs finite)
__device__ __forceinline__ unsigned short f2bf(float f) {
    union { float f; unsigned int u; } c; c.f = f;
    unsigned int r = c.u + 0x7FFFu + ((c.u >> 16) & 1u);
    return (unsigned short)(r >> 16);
}

// ---------------- elementwise convert: f32 -> bf16 (proven R8) ----------------
__global__ __launch_bounds__(256) void convert_f32_to_bf16(
    const float* __restrict__ in, unsigned short* __restrict__ out, int n)
{
    int idx = (blockIdx.x * 256 + threadIdx.x) * 8;
    const int stride = gridDim.x * 256 * 8;
    for (; idx < n; idx += stride) {
        const f32x4 a = *(const f32x4*)(in + idx);
        const f32x4 b = *(const f32x4*)(in + idx + 4);
        u16x8 o;
        #pragma unroll
        for (int q = 0; q < 4; ++q) { o[q] = f2bf(a[q]); o[q + 4] = f2bf(b[q]); }
        *(u16x8*)(out + idx) = o;
    }
}

// ---------------- main GEMM: 256x256, 8 waves, 4-phase counted-vmcnt, 32x32x16 ----------------
// LDS: buf c at c*32768 (ushort): A [256][64] at +0 (half h at +h*8192),
// B [256][64] at +16384 (half h at +16384+h*8192).
// T2 swizzle (both sides, rule #21): lds[row][col] = global[row][col ^ ((row&7)<<3)].
__global__ __launch_bounds__(512, 2) void linear_flh_gemm_256(
    const unsigned short* __restrict__ Xb,   // [M,K] bf16 bits (ws)
    const unsigned short* __restrict__ Wb,   // [N,K] bf16 bits (ws)
    const float* __restrict__ SX,            // [M]
    const float* __restrict__ SW,            // [N]
    const float* __restrict__ BIAS,          // [N]
    float* __restrict__ OUT)                 // [M,N] f32
{
    __shared__ unsigned short lds[65536];    // 128 KiB -> 1 workgroup/CU

    const int t    = threadIdx.x;     // 0..511
    const int lane = t & 63;
    const int wid  = t >> 6;          // 0..7
    const int qr   = wid >> 2;        // 0..1: wave-row within 128x128 quadrant
    const int wcol = wid & 3;         // 0..3: wave-col within quadrant
    const int l31  = lane & 31;       // 32x32 fragment row/col
    const int lhi  = lane >> 5;       // 0..1: k-half selector

    // R14 cluster map (bijective): XCD x owns M-band [4x,4x+4); 32 concurrent
    // CUs = 4x8 MxN patch -> 12 operand slices/K-tile (384 KB) L2-resident.
    const int bid = blockIdx.x;
    const int xcd = bid & 7;
    const int s   = bid >> 3;                 // 0..171
    const int tm  = xcd * 4 + (s & 3);        // 0..31
    const int tn  = s >> 2;                   // 0..42
    const int mBase = tm * BM;
    const int nBase = tn * BN;

    // 32x32x16 A/B frag: row|col = lane&31, k = (lane>>5)*8 + kk*16 + j.
    // Swizzled element col(kk) = (kk*16) ^ colK00 (bit-disjoint fields):
    const int colK00 = (lhi * 8) ^ ((lane & 7) << 3);

    f32x16 acc[4][2];   // [quadrant mh*2+nh][row-tile rt]
    #pragma unroll
    for (int q = 0; q < 4; ++q)
        #pragma unroll
        for (int rt = 0; rt < 2; ++rt)
            #pragma unroll
            for (int e = 0; e < 16; ++e)
                acc[q][rt][e] = 0.0f;

    // Stage one 128-row HALF (A or B) = 2 gload_lds(16B)/thread.
    // LDS dest linear (m104); global col pre-swizzled (rule #21).
    #define STAGE_HALF(P_, ROWB_, DSTB_, KCOL_)                                \
        { _Pragma("unroll")                                                    \
          for (int q_ = 0; q_ < 2; ++q_) {                                     \
              const int e_ = q_ * 4096 + t * 8;                                \
              const int r_ = e_ >> 6;                                          \
              const int c_ = ((t & 7) * 8) ^ ((r_ & 7) << 3);                  \
              __builtin_amdgcn_global_load_lds(                                \
                  (gmem_void*)((P_) + (size_t)((ROWB_) + r_) * K_DIM + (KCOL_) + c_),\
                  (lds_void*)(lds + (DSTB_) + e_), 16, 0, 0);                  \
          } }

    // A-half read: 2 row-tiles x 4 kk = 8 ds_read_b128. row&7 == lane&7.
    #define READ_A(DST_, HB_)                                                  \
        { _Pragma("unroll")                                                    \
          for (int rt_ = 0; rt_ < 2; ++rt_) {                                  \
              const int row_ = qr * 64 + rt_ * 32 + l31;                       \
              _Pragma("unroll")                                                \
              for (int kk_ = 0; kk_ < 4; ++kk_)                                \
                  DST_[rt_][kk_] = *(const bf16x8*)(lds + (HB_) + row_ * 64 +  \
                                                    ((kk_ * 16) ^ colK00));    \
          } }
    // B-half read: 1 col-tile x 4 kk = 4 ds_read_b128.
    #define READ_B(DST_, HB_)                                                  \
        { const int row_ = wcol * 32 + l31;                                    \
          _Pragma("unroll")                                                    \
          for (int kk_ = 0; kk_ < 4; ++kk_)                                    \
              DST_[kk_] = *(const bf16x8*)(lds + (HB_) + row_ * 64 +           \
                                           ((kk_ * 16) ^ colK00)); }

    // 8 x v_mfma_f32_32x32x16_bf16 per phase (2 row-tiles x 4 k-slices).
    #define MFMA_Q(Q_, AF_, BF_)                                               \
        { __builtin_amdgcn_s_setprio(1);                                       \
          _Pragma("unroll")                                                    \
          for (int rt_ = 0; rt_ < 2; ++rt_)                                    \
              _Pragma("unroll")                                                \
              for (int kk_ = 0; kk_ < 4; ++kk_)                                \
                  acc[Q_][rt_] = __builtin_amdgcn_mfma_f32_32x32x16_bf16(      \
                      AF_[rt_][kk_], BF_[kk_], acc[Q_][rt_], 0, 0, 0);         \
          __builtin_amdgcn_s_setprio(0); }

    #define WAITB(VM_)                                                         \
        asm volatile("s_waitcnt vmcnt(" VM_ ")" ::: "memory");                 \
        __builtin_amdgcn_s_barrier();                                          \
        asm volatile("" ::: "memory");

    // Prologue: tile 0 -> buf 0, halves [A0, B0, B1, A1] (8 loads in flight)
    STAGE_HALF(Xb, mBase,        0,             0);
    STAGE_HALF(Wb, nBase,        16384,         0);
    STAGE_HALF(Wb, nBase + 128,  16384 + 8192,  0);
    STAGE_HALF(Xb, mBase + 128,  8192,          0);

    // Main loop — R14 wait derivation unchanged (in-order VMEM retirement):
    //  ph0 vmcnt(4) certifies A0,B0; ph1 vmcnt(4) -> B1; ph2 vmcnt(4) -> A1;
    //  ph3 no wait (A1 certified at ph2).
    for (int kt = 0; kt < NT - 1; ++kt) {
        const int cur   = kt & 1;
        const int abase = cur * 32768;
        const int bbase = abase + 16384;
        const int ebase = (cur ^ 1) * 32768;
        const int kn    = (kt + 1) * BK;

        bf16x8 a0[2][4], a1[2][4], b0[4], b1[4];

        // ph0: q00 = A0 x B0
        WAITB("4");
        STAGE_HALF(Xb, mBase, ebase, kn);                       // A0'
        READ_A(a0, abase);
        READ_B(b0, bbase);
        MFMA_Q(0, a0, b0);

        // ph1: q01 = A0 x B1   (A0 carried in registers)
        WAITB("4");
        STAGE_HALF(Wb, nBase, ebase + 16384, kn);               // B0'
        READ_B(b1, bbase + 8192);
        MFMA_Q(1, a0, b1);

        // ph2: q11 = A1 x B1   (B1 carried)
        WAITB("4");
        STAGE_HALF(Wb, nBase + 128, ebase + 16384 + 8192, kn);  // B1'
        READ_A(a1, abase + 8192);
        MFMA_Q(3, a1, b1);

        // ph3: q10 = A1 x B0   (both carried; no wait, no barrier)
        STAGE_HALF(Xb, mBase + 128, ebase + 8192, kn);          // A1'
        MFMA_Q(2, a1, b0);
    }

    // Tail iter kt = NT-1: no staging -> reduced counts (4,2,0).
    {
        const int abase = ((NT - 1) & 1) * 32768;
        const int bbase = abase + 16384;
        bf16x8 a0[2][4], a1[2][4], b0[4], b1[4];

        WAITB("4");                       // A0,B0 landed
        READ_A(a0, abase);
        READ_B(b0, bbase);
        MFMA_Q(0, a0, b0);

        WAITB("2");                       // B1 landed
        READ_B(b1, bbase + 8192);
        MFMA_Q(1, a0, b1);

        WAITB("0");                       // A1 landed
        READ_A(a1, abase + 8192);
        MFMA_Q(3, a1, b1);

        MFMA_Q(2, a1, b0);
    }

    #undef WAITB
    #undef MFMA_Q
    #undef READ_B
    #undef READ_A
    #undef STAGE_HALF

    // Epilogue: out = acc * sx[row] * sw[col] + bias[col]; NT stores.
    // 32x32 C/D layout: col = lane&31, row = (reg&3) + 8*(reg>>2) + 4*(lane>>5)
    // (m74/m101 verified). Hoist SX per (mh,rt) row-block.
    #pragma unroll
    for (int mh = 0; mh < 2; ++mh) {
        #pragma unroll
        for (int rt = 0; rt < 2; ++rt) {
            const int R = mBase + mh * 128 + qr * 64 + rt * 32;
            float sxv[16];
            #pragma unroll
            for (int rg = 0; rg < 16; ++rg)
                sxv[rg] = SX[R + (rg & 3) + 8 * (rg >> 2) + 4 * lhi];
            #pragma unroll
            for (int nh = 0; nh < 2; ++nh) {
                const int q = mh * 2 + nh;
                const int C = nBase + nh * 128 + wcol * 32 + l31;
                const float swv = SW[C];
                const float bv  = BIAS[C];
                #pragma unroll
                for (int rg = 0; rg < 16; ++rg) {
                    const int row = R + (rg & 3) + 8 * (rg >> 2) + 4 * lhi;
                    float v = acc[q][rt][rg] * sxv[rg] * swv + bv;
                    v = fminf(fmaxf(v, -1.0e5f), 1.0e5f);   // diagnostic sentinel
                    __builtin_nontemporal_store(v, OUT + (size_t)row * N_DIM + C);
                }
            }
        }
    }
}

// ---------------- fallback (R7/R8-proven): inline-convert reg-staged 128^2 ----------------
#define FBM 128
#define FBK 64
__global__ __launch_bounds__(256) void linear_flh_gemm_f32in(
    const float* __restrict__ X, const float* __restrict__ SX,
    const float* __restrict__ W, const float* __restrict__ SW,
    const float* __restrict__ BIAS, float* __restrict__ OUT)
{
    __shared__ alignas(16) unsigned short smA[FBM * FBK];
    __shared__ alignas(16) unsigned short smB[FBM * FBK];
    const int t = threadIdx.x;
    const int lane = t & 63, wave = t >> 6;
    const int wr = wave >> 1, wc = wave & 1;
    int bid = blockIdx.x;
    bid = (bid & 7) * ((M_DIM / FBM) * (N_DIM / FBM) / 8) + (bid >> 3);
    const int mBase = (bid / (N_DIM / FBM)) * FBM;
    const int nBase = (bid % (N_DIM / FBM)) * FBM;
    const int cl = lane & 15, rl = lane >> 4;
    f32x4 acc[4][4];
    #pragma unroll
    for (int i = 0; i < 4; ++i)
        #pragma unroll
        for (int j = 0; j < 4; ++j) acc[i][j] = (f32x4){0.f, 0.f, 0.f, 0.f};
    for (int kt = 0; kt < K_DIM / FBK; ++kt) {
        const int kBase = kt * FBK;
        f32x4 ra[8], rb[8];
        #pragma unroll
        for (int cc = 0; cc < 8; ++cc) {
            const int e = cc * 1024 + t * 4;
            const int r = e >> 6, c = e & 63;
            ra[cc] = *(const f32x4*)(X + (size_t)(mBase + r) * K_DIM + kBase + c);
            rb[cc] = *(const f32x4*)(W + (size_t)(nBase + r) * K_DIM + kBase + c);
        }
        __syncthreads();
        #pragma unroll
        for (int cc = 0; cc < 8; ++cc) {
            const int e = cc * 1024 + t * 4;
            u16x4 pa, pb;
            #pragma unroll
            for (int q = 0; q < 4; ++q) { pa[q] = f2bf(ra[cc][q]); pb[q] = f2bf(rb[cc][q]); }
            *(u16x4*)(smA + e) = pa;
            *(u16x4*)(smB + e) = pb;
        }
        __syncthreads();
        #pragma unroll
        for (int kk = 0; kk < FBK / 32; ++kk) {
            bf16x8 afr[4], bfr[4];
            #pragma unroll
            for (int i = 0; i < 4; ++i) {
                afr[i] = *(const bf16x8*)(smA + (wr * 64 + i * 16 + cl) * FBK + kk * 32 + rl * 8);
                bfr[i] = *(const bf16x8*)(smB + (wc * 64 + i * 16 + cl) * FBK + kk * 32 + rl * 8);
            }
            #pragma unroll
            for (int i = 0; i < 4; ++i)
                #pragma unroll
                for (int j = 0; j < 4; ++j)
                    acc[i][j] = __builtin_amdgcn_mfma_f32_16x16x32_bf16(
                        afr[i], bfr[j], acc[i][j], 0, 0, 0);
        }
    }
    #pragma unroll
    for (int j = 0; j < 4; ++j) {
        const int gn = nBase + wc * 64 + j * 16 + cl;
        const float swv = SW[gn], bv = BIAS[gn];
        #pragma unroll
        for (int i = 0; i < 4; ++i) {
            const int gmb = mBase + wr * 64 + i * 16 + rl * 4;
            #pragma unroll
            for (int r = 0; r < 4; ++r) {
                float v = acc[i][j][r] * SX[gmb + r] * swv + bv;
                v = fminf(fmaxf(v, -1.0e5f), 1.0e5f);
                OUT[(size_t)(gmb + r) * N_DIM + gn] = v;
            }
        }
    }
}

extern "C" void kernel_launch(void* const* d_in, const int* in_sizes, int n_in,
                              void* d_out, int out_size, void* d_ws, size_t ws_size,
                              hipStream_t stream) {
    const void* pX = d_in[0]; const void* pSX = d_in[1]; const void* pW = d_in[2];
    const void* pSW = d_in[3]; const void* pBS = d_in[4];
    for (int i = 0; i < n_in; ++i) {
        if (in_sizes[i] == M_DIM * K_DIM)      pX  = d_in[i];
        else if (in_sizes[i] == M_DIM)         pSX = d_in[i];
        else if (in_sizes[i] == N_DIM * K_DIM) pW  = d_in[i];
    }
    {
        int first = -1, second = -1;
        for (int i = 0; i < n_in; ++i)
            if (in_sizes[i] == N_DIM) { if (first < 0) first = i; else if (second < 0) second = i; }
        if (first >= 0)  pSW = d_in[first];
        if (second >= 0) pBS = d_in[second];
    }

    if (ws_size >= WS_NEEDED) {
        unsigned short* Xb = (unsigned short*)d_ws;
        unsigned short* Wb = Xb + X_ELEMS;
        convert_f32_to_bf16<<<2048, 256, 0, stream>>>((const float*)pX, Xb, X_ELEMS);
        convert_f32_to_bf16<<<2048, 256, 0, stream>>>((const float*)pW, Wb, W_ELEMS);
        linear_flh_gemm_256<<<dim3(NWG), 512, 0, stream>>>(
            Xb, Wb, (const float*)pSX, (const float*)pSW, (const float*)pBS,
            (float*)d_out);
    } else {
        dim3 grid((M_DIM / FBM) * (N_DIM / FBM));
        linear_flh_gemm_f32in<<<grid, 256, 0, stream>>>(
            (const float*)pX, (const float*)pSX, (const float*)pW,
            (const float*)pSW, (const float*)pBS, (float*)d_out);
    }
}

// Round 17
// 716.454 us; speedup vs baseline: 1.1072x; 1.1072x over previous
//
#include <hip/hip_runtime.h>
#include <hip/hip_bf16.h>

// LinearFLH: out[m,n] = sx[m]*sw[n]*(x[m,:].w[n,:]) + bias[n]
// M=8192, N=11008, K=4096. All harness buffers FLOAT32 (fp16 ref -> "else
// float" rule). Pipeline: (1) f32->bf16 convert of X,W into d_ws, (2) 256x256
// BK=64 bf16 MFMA GEMM, 8 waves, R14 champion schedule (4-phase, 1 barrier/
// phase, counted vmcnt, K-synchronized 2D cluster map, 16x16x32 MFMA) +
// *** 2-TILE-AHEAD LAG-STAGING (m201 pipeline depth) ***:
//   tile t+2 staged into buf t&1 (the one being read), each half at the phase
//   AFTER its last read (A0,B0@ph1, B1@ph2, A1@ph3). WAR: 1-barrier phases +
//   compiler auto-lgkmcnt => all waves' reads of a region complete before the
//   barrier behind which its overwrite is issued. RAW waits derived by
//   loads-issued-after counting: ph0 vmcnt(12), ph1 vmcnt(10), ph2 vmcnt(12),
//   ph3 none -- each certified half has ~2 iters (~10k cy) of slack -> free.
// R16 lesson: 32x32x16 frag reads = 4-way bank conflict (6.8e7), reverted.

#define M_DIM 8192
#define N_DIM 11008
#define K_DIM 4096
#define BM 256
#define BN 256
#define BK 64
#define NT (K_DIM / BK)                       // 64 K-tiles
#define NWG ((M_DIM / BM) * (N_DIM / BN))     // 32*43 = 1376

#define X_ELEMS (M_DIM * K_DIM)
#define W_ELEMS (N_DIM * K_DIM)
#define WS_NEEDED ((size_t)(X_ELEMS + W_ELEMS) * 2)

typedef __bf16 bf16x8 __attribute__((ext_vector_type(8)));
typedef float f32x4 __attribute__((ext_vector_type(4)));
typedef unsigned short u16x4 __attribute__((ext_vector_type(4)));
typedef unsigned short u16x8 __attribute__((ext_vector_type(8)));

typedef __attribute__((address_space(3))) void lds_void;
typedef const __attribute__((address_space(1))) void gmem_void;

// f32 -> bf16 bits, round-to-nearest-even (inputs finite)
__device__ __forceinline__ unsigned short f2bf(float f) {
    union { float f; unsigned int u; } c; c.f = f;
    unsigned int r = c.u + 0x7FFFu + ((c.u >> 16) & 1u);
    return (unsigned short)(r >> 16);
}

// ---------------- elementwise convert: f32 -> bf16 (proven R8) ----------------
__global__ __launch_bounds__(256) void convert_f32_to_bf16(
    const float* __restrict__ in, unsigned short* __restrict__ out, int n)
{
    int idx = (blockIdx.x * 256 + threadIdx.x) * 8;
    const int stride = gridDim.x * 256 * 8;
    for (; idx < n; idx += stride) {
        const f32x4 a = *(const f32x4*)(in + idx);
        const f32x4 b = *(const f32x4*)(in + idx + 4);
        u16x8 o;
        #pragma unroll
        for (int q = 0; q < 4; ++q) { o[q] = f2bf(a[q]); o[q + 4] = f2bf(b[q]); }
        *(u16x8*)(out + idx) = o;
    }
}

// ---------------- main GEMM: 256x256, 8 waves, 4-phase, 2-ahead lag-staging ----------------
// LDS: buf c at c*32768 (ushort): A [256][64] at +0 (half h at +h*8192),
// B [256][64] at +16384 (half h at +16384+h*8192).
// T2 swizzle (both sides, rule #21): lds[row][col] = global[row][col ^ ((row&7)<<3)].
__global__ __launch_bounds__(512, 2) void linear_flh_gemm_256(
    const unsigned short* __restrict__ Xb,   // [M,K] bf16 bits (ws)
    const unsigned short* __restrict__ Wb,   // [N,K] bf16 bits (ws)
    const float* __restrict__ SX,            // [M]
    const float* __restrict__ SW,            // [N]
    const float* __restrict__ BIAS,          // [N]
    float* __restrict__ OUT)                 // [M,N] f32
{
    __shared__ unsigned short lds[65536];    // 128 KiB -> 1 workgroup/CU

    const int t    = threadIdx.x;     // 0..511
    const int lane = t & 63;
    const int wid  = t >> 6;          // 0..7
    const int qr   = wid >> 2;        // 0..1: wave-row within 128x128 quadrant
    const int wcol = wid & 3;         // 0..3: wave-col within quadrant
    const int cl   = lane & 15;       // fragment row/col
    const int rl   = lane >> 4;       // 0..3: k-group

    // R14 cluster map (bijective): XCD x owns M-band [4x,4x+4); 32 concurrent
    // CUs = 4x8 MxN patch -> 12 operand slices/K-tile (384 KB) L2-resident.
    const int bid = blockIdx.x;
    const int xcd = bid & 7;
    const int s   = bid >> 3;                 // 0..171
    const int tm  = xcd * 4 + (s & 3);        // 0..31
    const int tn  = s >> 2;                   // 0..42
    const int mBase = tm * BM;
    const int nBase = tn * BN;

    // T2 read-side: element col = (k0) ^ ((row&7)<<3); row&7 == cl&7 below.
    const int colK0 = (rl * 8) ^ ((cl & 7) << 3);
    const int colK1 = colK0 ^ 32;

    f32x4 acc[4][4][2];   // [quadrant mh*2+nh][mi][ni]
    #pragma unroll
    for (int q = 0; q < 4; ++q)
        #pragma unroll
        for (int mi = 0; mi < 4; ++mi)
            #pragma unroll
            for (int ni = 0; ni < 2; ++ni)
                acc[q][mi][ni] = (f32x4){0.f, 0.f, 0.f, 0.f};

    // Stage one 128-row HALF (A or B) = 2 gload_lds(16B)/thread.
    // LDS dest linear (m104); global col pre-swizzled (rule #21).
    #define STAGE_HALF(P_, ROWB_, DSTB_, KCOL_)                                \
        { _Pragma("unroll")                                                    \
          for (int q_ = 0; q_ < 2; ++q_) {                                     \
              const int e_ = q_ * 4096 + t * 8;                                \
              const int r_ = e_ >> 6;                                          \
              const int c_ = ((t & 7) * 8) ^ ((r_ & 7) << 3);                  \
              __builtin_amdgcn_global_load_lds(                                \
                  (gmem_void*)((P_) + (size_t)((ROWB_) + r_) * K_DIM + (KCOL_) + c_),\
                  (lds_void*)(lds + (DSTB_) + e_), 16, 0, 0);                  \
          } }

    #define READ_A(DST_, HB_)                                                  \
        { _Pragma("unroll")                                                    \
          for (int mi_ = 0; mi_ < 4; ++mi_) {                                  \
              const int row_ = qr * 64 + mi_ * 16 + cl;                        \
              DST_[mi_][0] = *(const bf16x8*)(lds + (HB_) + row_ * 64 + colK0);\
              DST_[mi_][1] = *(const bf16x8*)(lds + (HB_) + row_ * 64 + colK1);\
          } }
    #define READ_B(DST_, HB_)                                                  \
        { _Pragma("unroll")                                                    \
          for (int ni_ = 0; ni_ < 2; ++ni_) {                                  \
              const int row_ = wcol * 32 + ni_ * 16 + cl;                      \
              DST_[ni_][0] = *(const bf16x8*)(lds + (HB_) + row_ * 64 + colK0);\
              DST_[ni_][1] = *(const bf16x8*)(lds + (HB_) + row_ * 64 + colK1);\
          } }

    #define MFMA_Q(Q_, AF_, BF_)                                               \
        { __builtin_amdgcn_s_setprio(1);                                       \
          _Pragma("unroll")                                                    \
          for (int mi_ = 0; mi_ < 4; ++mi_)                                    \
              _Pragma("unroll")                                                \
              for (int ni_ = 0; ni_ < 2; ++ni_) {                              \
                  acc[Q_][mi_][ni_] = __builtin_amdgcn_mfma_f32_16x16x32_bf16( \
                      AF_[mi_][0], BF_[ni_][0], acc[Q_][mi_][ni_], 0, 0, 0);   \
                  acc[Q_][mi_][ni_] = __builtin_amdgcn_mfma_f32_16x16x32_bf16( \
                      AF_[mi_][1], BF_[ni_][1], acc[Q_][mi_][ni_], 0, 0, 0);   \
              }                                                                \
          __builtin_amdgcn_s_setprio(0); }

    #define WAITB(VM_)                                                         \
        asm volatile("s_waitcnt vmcnt(" VM_ ")" ::: "memory");                 \
        __builtin_amdgcn_s_barrier();                                          \
        asm volatile("" ::: "memory");

    // Prologue: stage tiles 0 and 1 (16 loads), halves [A0,B0,B1,A1] each.
    STAGE_HALF(Xb, mBase,        0,                     0);
    STAGE_HALF(Wb, nBase,        16384,                 0);
    STAGE_HALF(Wb, nBase + 128,  16384 + 8192,          0);
    STAGE_HALF(Xb, mBase + 128,  8192,                  0);
    STAGE_HALF(Xb, mBase,        32768,                 BK);
    STAGE_HALF(Wb, nBase,        32768 + 16384,         BK);
    STAGE_HALF(Wb, nBase + 128,  32768 + 16384 + 8192,  BK);
    STAGE_HALF(Xb, mBase + 128,  32768 + 8192,          BK);

    // Main loop. RAW wait derivation (loads-issued-after, in-order retirement):
    //  A0,B0(t) staged iter t-2 ph1 -> 12 newer loads -> ph0 vmcnt(12)
    //  B1(t)    staged iter t-2 ph2 -> 10 newer       -> ph1 vmcnt(10)
    //  A1(t)    staged iter t-2 ph3 -> 12 newer       -> ph2 vmcnt(12)
    //  ph3: nothing needed -> no wait/barrier.
    // Uniform from iter 0 (prologue = "iters -2,-1" stage pattern) and through
    // the tail (kn2 wraps to 0: garbage into dead halves, never read).
    for (int kt = 0; kt < NT; ++kt) {
        const int cur   = kt & 1;
        const int abase = cur * 32768;
        const int bbase = abase + 16384;
        const int kn2   = (kt + 2 < NT) ? (kt + 2) * BK : 0;   // 2-ahead (wrapped)

        bf16x8 a0[4][2], a1[4][2], b0[2][2], b1[2][2];

        // ph0: q00 = A0 x B0 (no staging)
        WAITB("12");
        READ_A(a0, abase);
        READ_B(b0, bbase);
        MFMA_Q(0, a0, b0);

        // ph1: q01 = A0 x B1; stage A0'',B0'' into their (dead) regions
        WAITB("10");
        STAGE_HALF(Xb, mBase, abase, kn2);                      // A0''
        STAGE_HALF(Wb, nBase, bbase, kn2);                      // B0''
        READ_B(b1, bbase + 8192);
        MFMA_Q(1, a0, b1);

        // ph2: q11 = A1 x B1; stage B1'' (B1 region dead after ph1)
        WAITB("12");
        STAGE_HALF(Wb, nBase + 128, bbase + 8192, kn2);         // B1''
        READ_A(a1, abase + 8192);
        MFMA_Q(3, a1, b1);

        // ph3: q10 = A1 x B0; stage A1'' (A1 region dead); no wait/barrier
        STAGE_HALF(Xb, mBase + 128, abase + 8192, kn2);         // A1''
        MFMA_Q(2, a1, b0);
    }

    // Drain outstanding (garbage) DMAs before LDS goes out of scope.
    asm volatile("s_waitcnt vmcnt(0)" ::: "memory");

    #undef WAITB
    #undef MFMA_Q
    #undef READ_B
    #undef READ_A
    #undef STAGE_HALF

    // Epilogue: out = acc * sx[row] * sw[col] + bias[col]; NT stores.
    // C/D layout: col = lane&15, row = rl*4 + reg (m89/m91).
    #pragma unroll
    for (int q = 0; q < 4; ++q) {
        const int mh = q >> 1, nh = q & 1;
        #pragma unroll
        for (int mi = 0; mi < 4; ++mi) {
            const int rowb = mBase + mh * 128 + qr * 64 + mi * 16 + rl * 4;
            #pragma unroll
            for (int ni = 0; ni < 2; ++ni) {
                const int col = nBase + nh * 128 + wcol * 32 + ni * 16 + cl;
                const float swv = SW[col];
                const float bv  = BIAS[col];
                #pragma unroll
                for (int rr = 0; rr < 4; ++rr) {
                    const int row = rowb + rr;
                    float v = acc[q][mi][ni][rr] * SX[row] * swv + bv;
                    v = fminf(fmaxf(v, -1.0e5f), 1.0e5f);   // diagnostic sentinel
                    __builtin_nontemporal_store(v, OUT + (size_t)row * N_DIM + col);
                }
            }
        }
    }
}

// ---------------- fallback (R7/R8-proven): inline-convert reg-staged 128^2 ----------------
#define FBM 128
#define FBK 64
__global__ __launch_bounds__(256) void linear_flh_gemm_f32in(
    const float* __restrict__ X, const float* __restrict__ SX,
    const float* __restrict__ W, const float* __restrict__ SW,
    const float* __restrict__ BIAS, float* __restrict__ OUT)
{
    __shared__ alignas(16) unsigned short smA[FBM * FBK];
    __shared__ alignas(16) unsigned short smB[FBM * FBK];
    const int t = threadIdx.x;
    const int lane = t & 63, wave = t >> 6;
    const int wr = wave >> 1, wc = wave & 1;
    int bid = blockIdx.x;
    bid = (bid & 7) * ((M_DIM / FBM) * (N_DIM / FBM) / 8) + (bid >> 3);
    const int mBase = (bid / (N_DIM / FBM)) * FBM;
    const int nBase = (bid % (N_DIM / FBM)) * FBM;
    const int cl = lane & 15, rl = lane >> 4;
    f32x4 acc[4][4];
    #pragma unroll
    for (int i = 0; i < 4; ++i)
        #pragma unroll
        for (int j = 0; j < 4; ++j) acc[i][j] = (f32x4){0.f, 0.f, 0.f, 0.f};
    for (int kt = 0; kt < K_DIM / FBK; ++kt) {
        const int kBase = kt * FBK;
        f32x4 ra[8], rb[8];
        #pragma unroll
        for (int cc = 0; cc < 8; ++cc) {
            const int e = cc * 1024 + t * 4;
            const int r = e >> 6, c = e & 63;
            ra[cc] = *(const f32x4*)(X + (size_t)(mBase + r) * K_DIM + kBase + c);
            rb[cc] = *(const f32x4*)(W + (size_t)(nBase + r) * K_DIM + kBase + c);
        }
        __syncthreads();
        #pragma unroll
        for (int cc = 0; cc < 8; ++cc) {
            const int e = cc * 1024 + t * 4;
            u16x4 pa, pb;
            #pragma unroll
            for (int q = 0; q < 4; ++q) { pa[q] = f2bf(ra[cc][q]); pb[q] = f2bf(rb[cc][q]); }
            *(u16x4*)(smA + e) = pa;
            *(u16x4*)(smB + e) = pb;
        }
        __syncthreads();
        #pragma unroll
        for (int kk = 0; kk < FBK / 32; ++kk) {
            bf16x8 afr[4], bfr[4];
            #pragma unroll
            for (int i = 0; i < 4; ++i) {
                afr[i] = *(const bf16x8*)(smA + (wr * 64 + i * 16 + cl) * FBK + kk * 32 + rl * 8);
                bfr[i] = *(const bf16x8*)(smB + (wc * 64 + i * 16 + cl) * FBK + kk * 32 + rl * 8);
            }
            #pragma unroll
            for (int i = 0; i < 4; ++i)
                #pragma unroll
                for (int j = 0; j < 4; ++j)
                    acc[i][j] = __builtin_amdgcn_mfma_f32_16x16x32_bf16(
                        afr[i], bfr[j], acc[i][j], 0, 0, 0);
        }
    }
    #pragma unroll
    for (int j = 0; j < 4; ++j) {
        const int gn = nBase + wc * 64 + j * 16 + cl;
        const float swv = SW[gn], bv = BIAS[gn];
        #pragma unroll
        for (int i = 0; i < 4; ++i) {
            const int gmb = mBase + wr * 64 + i * 16 + rl * 4;
            #pragma unroll
            for (int r = 0; r < 4; ++r) {
                float v = acc[i][j][r] * SX[gmb + r] * swv + bv;
                v = fminf(fmaxf(v, -1.0e5f), 1.0e5f);
                OUT[(size_t)(gmb + r) * N_DIM + gn] = v;
            }
        }
    }
}

extern "C" void kernel_launch(void* const* d_in, const int* in_sizes, int n_in,
                              void* d_out, int out_size, void* d_ws, size_t ws_size,
                              hipStream_t stream) {
    const void* pX = d_in[0]; const void* pSX = d_in[1]; const void* pW = d_in[2];
    const void* pSW = d_in[3]; const void* pBS = d_in[4];
    for (int i = 0; i < n_in; ++i) {
        if (in_sizes[i] == M_DIM * K_DIM)      pX  = d_in[i];
        else if (in_sizes[i] == M_DIM)         pSX = d_in[i];
        else if (in_sizes[i] == N_DIM * K_DIM) pW  = d_in[i];
    }
    {
        int first = -1, second = -1;
        for (int i = 0; i < n_in; ++i)
            if (in_sizes[i] == N_DIM) { if (first < 0) first = i; else if (second < 0) second = i; }
        if (first >= 0)  pSW = d_in[first];
        if (second >= 0) pBS = d_in[second];
    }

    if (ws_size >= WS_NEEDED) {
        unsigned short* Xb = (unsigned short*)d_ws;
        unsigned short* Wb = Xb + X_ELEMS;
        convert_f32_to_bf16<<<2048, 256, 0, stream>>>((const float*)pX, Xb, X_ELEMS);
        convert_f32_to_bf16<<<2048, 256, 0, stream>>>((const float*)pW, Wb, W_ELEMS);
        linear_flh_gemm_256<<<dim3(NWG), 512, 0, stream>>>(
            Xb, Wb, (const float*)pSX, (const float*)pSW, (const float*)pBS,
            (float*)d_out);
    } else {
        dim3 grid((M_DIM / FBM) * (N_DIM / FBM));
        linear_flh_gemm_f32in<<<grid, 256, 0, stream>>>(
            (const float*)pX, (const float*)pSX, (const float*)pW,
            (const float*)pSW, (const float*)pBS, (float*)d_out);
    }
}